// Round 3
// baseline (456.863 us; speedup 1.0000x reference)
//
#include <hip/hip_runtime.h>

// GCN 2-layer: x[N,128] -> GCNConv(W1[128,64], b1) -> ReLU -> GCNConv(W2[64,32], b2)
// norm = dinv[src]*dinv[dst] factorized: pre-scale h by dinv, aggregate, post-scale.
// CSR (by dst) built once per call, reused by both layers.
// R3: CSR build kernels process 4 edges/thread with int4 index loads -> 4x MLP
// (R2 showed k_fill latency-bound: VALUBusy 0.55%, HBM 12%, 1 chain/lane).

#define BLK 256

__device__ __forceinline__ float4 shfl_xor4(float4 v, int m) {
    v.x = __shfl_xor(v.x, m, 64);
    v.y = __shfl_xor(v.y, m, 64);
    v.z = __shfl_xor(v.z, m, 64);
    v.w = __shfl_xor(v.w, m, 64);
    return v;
}
__device__ __forceinline__ void add4(float4& a, const float4 b) {
    a.x += b.x; a.y += b.y; a.z += b.z; a.w += b.w;
}

// int64-layout detection, wave-uniform, L2-hot: odd 32-bit words of the first
// 16 values are all zero iff indices are little-endian int64.
__device__ __forceinline__ bool detect64(const int* __restrict__ idx) {
    int z = 0;
#pragma unroll
    for (int i = 1; i < 32; i += 2) z |= idx[i];
    return z == 0;
}

// ---- degree count: 4 edges/thread, vectorized dst loads, 4 atomics in flight
__global__ void k_count(const int* __restrict__ idx, int* __restrict__ counts, int E) {
    bool is64 = detect64(idx);
    int e0 = (blockIdx.x * blockDim.x + threadIdx.x) * 4;
    if (e0 >= E) return;
    if (e0 + 3 < E) {
        int d0, d1, d2, d3;
        if (!is64) {
            int4 d = *(const int4*)&idx[E + e0];
            d0 = d.x; d1 = d.y; d2 = d.z; d3 = d.w;
        } else {
            const int4* p = (const int4*)&idx[2 * (E + e0)];
            int4 a = p[0], b = p[1];
            d0 = a.x; d1 = a.z; d2 = b.x; d3 = b.z;
        }
        atomicAdd(&counts[d0], 1);
        atomicAdd(&counts[d1], 1);
        atomicAdd(&counts[d2], 1);
        atomicAdd(&counts[d3], 1);
    } else {
        for (int e = e0; e < E; ++e) {
            int d = is64 ? idx[2 * (E + e)] : idx[E + e];
            atomicAdd(&counts[d], 1);
        }
    }
}

// ---- 3-phase exclusive scan of counts[N] -> row_ptr[N+1]; scan1 also emits dinv
__global__ void k_scan1(const int* __restrict__ counts, int* __restrict__ bsums,
                        float* __restrict__ dinv, int N) {
    __shared__ int s[256];
    int i = blockIdx.x * 256 + threadIdx.x;
    int c = (i < N) ? counts[i] : 0;
    if (i < N) dinv[i] = rsqrtf((float)(c + 1));  // +1 self-loop; always > 0
    s[threadIdx.x] = c;
    __syncthreads();
    for (int st = 128; st > 0; st >>= 1) {
        if (threadIdx.x < st) s[threadIdx.x] += s[threadIdx.x + st];
        __syncthreads();
    }
    if (threadIdx.x == 0) bsums[blockIdx.x] = s[0];
}

__global__ void k_scan2(const int* __restrict__ bsums, int* __restrict__ boffs, int nb) {
    __shared__ int s[512];
    int t = threadIdx.x;
    s[t] = (t < nb) ? bsums[t] : 0;
    __syncthreads();
    for (int st = 1; st < 512; st <<= 1) {
        int v = (t >= st) ? s[t - st] : 0;
        __syncthreads();
        s[t] += v;
        __syncthreads();
    }
    boffs[t] = (t == 0) ? 0 : s[t - 1];  // exclusive
}

__global__ void k_scan3(const int* __restrict__ counts, const int* __restrict__ boffs,
                        int* __restrict__ row_ptr, int* __restrict__ cursor, int N, int E) {
    __shared__ int s[256];
    int i = blockIdx.x * 256 + threadIdx.x;
    int v = (i < N) ? counts[i] : 0;
    s[threadIdx.x] = v;
    __syncthreads();
    for (int st = 1; st < 256; st <<= 1) {
        int u = (threadIdx.x >= st) ? s[threadIdx.x - st] : 0;
        __syncthreads();
        s[threadIdx.x] += u;
        __syncthreads();
    }
    if (i < N) {
        row_ptr[i] = boffs[blockIdx.x] + s[threadIdx.x] - v;  // exclusive
        cursor[i] = 0;                                        // zero fill-cursor here
    }
    if (i == 0) row_ptr[N] = E;
}

// ---- CSR fill: 4 edges/thread, 4 independent atomic->store chains in flight
__global__ void k_fill(const int* __restrict__ idx, const int* __restrict__ row_ptr,
                       int* __restrict__ cursor, int* __restrict__ csr_src, int E) {
    bool is64 = detect64(idx);
    int e0 = (blockIdx.x * blockDim.x + threadIdx.x) * 4;
    if (e0 >= E) return;
    if (e0 + 3 < E) {
        int s0, s1, s2, s3, d0, d1, d2, d3;
        if (!is64) {
            int4 sv = *(const int4*)&idx[e0];
            int4 dv = *(const int4*)&idx[E + e0];
            s0 = sv.x; s1 = sv.y; s2 = sv.z; s3 = sv.w;
            d0 = dv.x; d1 = dv.y; d2 = dv.z; d3 = dv.w;
        } else {
            const int4* ps = (const int4*)&idx[2 * e0];
            const int4* pd = (const int4*)&idx[2 * (E + e0)];
            int4 a = ps[0], b = ps[1], c = pd[0], d = pd[1];
            s0 = a.x; s1 = a.z; s2 = b.x; s3 = b.z;
            d0 = c.x; d1 = c.z; d2 = d.x; d3 = d.z;
        }
        int r0 = row_ptr[d0], r1 = row_ptr[d1], r2 = row_ptr[d2], r3 = row_ptr[d3];
        int p0 = atomicAdd(&cursor[d0], 1);
        int p1 = atomicAdd(&cursor[d1], 1);
        int p2 = atomicAdd(&cursor[d2], 1);
        int p3 = atomicAdd(&cursor[d3], 1);
        csr_src[r0 + p0] = s0;
        csr_src[r1 + p1] = s1;
        csr_src[r2 + p2] = s2;
        csr_src[r3 + p3] = s3;
    } else {
        for (int e = e0; e < E; ++e) {
            int s_ = is64 ? idx[2 * e] : idx[e];
            int d_ = is64 ? idx[2 * (E + e)] : idx[E + e];
            int pos = atomicAdd(&cursor[d_], 1);
            csr_src[row_ptr[d_] + pos] = s_;
        }
    }
}

// ---- layer 1 GEMM: hs1[i,f] = (sum_k x[i,k] * W1[k,f]) * dinv[i], f in [0,64)
__global__ void k_gemm1(const float* __restrict__ x, const float* __restrict__ W1,
                        const float* __restrict__ dinv, float* __restrict__ hs1, int N) {
    __shared__ float xs[16][128];
    int tid = threadIdx.x;
    int rbase = blockIdx.x * 16;
    const float4* xv = (const float4*)x;  // row r at xv[r*32 + c]
    for (int i = tid; i < 512; i += 256) {
        int r = i >> 5, c = i & 31;
        int rr = rbase + r;
        if (rr >= N) rr = N - 1;
        ((float4*)&xs[r][0])[c] = xv[(size_t)rr * 32 + c];
    }
    __syncthreads();
    int f = tid & 63;
    int rs = tid >> 6;  // 0..3
    float a0 = 0.f, a1_ = 0.f, a2 = 0.f, a3 = 0.f;
#pragma unroll 4
    for (int k = 0; k < 128; ++k) {
        float w = W1[k * 64 + f];
        a0 = fmaf(xs[rs][k], w, a0);
        a1_ = fmaf(xs[rs + 4][k], w, a1_);
        a2 = fmaf(xs[rs + 8][k], w, a2);
        a3 = fmaf(xs[rs + 12][k], w, a3);
    }
    int r;
    r = rbase + rs;      if (r < N) hs1[(size_t)r * 64 + f] = a0 * dinv[r];
    r = rbase + rs + 4;  if (r < N) hs1[(size_t)r * 64 + f] = a1_ * dinv[r];
    r = rbase + rs + 8;  if (r < N) hs1[(size_t)r * 64 + f] = a2 * dinv[r];
    r = rbase + rs + 12; if (r < N) hs1[(size_t)r * 64 + f] = a3 * dinv[r];
}

// ---- layer 1 aggregation: one wave per node; 4 groups x 16 lanes, unroll 2
// -> 8 independent 256B row gathers in flight per wave.
__global__ void k_agg1(const float* __restrict__ hs1, const int* __restrict__ row_ptr,
                       const int* __restrict__ csr_src, const float* __restrict__ dinv,
                       const float* __restrict__ b1, float* __restrict__ a1, int N) {
    int node = (blockIdx.x * blockDim.x + threadIdx.x) >> 6;
    if (node >= N) return;
    int lane = threadIdx.x & 63;
    int g = lane >> 4;    // edge slot 0..3
    int c = lane & 15;    // float4 column
    const float4* H = (const float4*)hs1;  // row i at H[i*16 + c]

    float4 acc = {0.f, 0.f, 0.f, 0.f}, accB = {0.f, 0.f, 0.f, 0.f};
    if (g == 0) acc = H[(size_t)node * 16 + c];  // self-loop (pre-scaled by dinv)

    int beg = row_ptr[node], end = row_ptr[node + 1];
    int e = beg + g;
    for (; e + 4 < end; e += 8) {
        int j0 = csr_src[e];
        int j1 = csr_src[e + 4];
        float4 v0 = H[(size_t)j0 * 16 + c];
        float4 v1 = H[(size_t)j1 * 16 + c];
        add4(acc, v0);
        add4(accB, v1);
    }
    if (e < end) {
        int j = csr_src[e];
        add4(acc, H[(size_t)j * 16 + c]);
    }
    add4(acc, accB);
    add4(acc, shfl_xor4(acc, 16));
    add4(acc, shfl_xor4(acc, 32));
    if (g == 0) {
        float s = dinv[node];
        float4 bv = ((const float4*)b1)[c];
        float4 o;
        o.x = fmaxf(fmaf(acc.x, s, bv.x), 0.f);
        o.y = fmaxf(fmaf(acc.y, s, bv.y), 0.f);
        o.z = fmaxf(fmaf(acc.z, s, bv.z), 0.f);
        o.w = fmaxf(fmaf(acc.w, s, bv.w), 0.f);
        ((float4*)a1)[(size_t)node * 16 + c] = o;
    }
}

// ---- layer 2 GEMM: hs2[i,f] = (sum_k a1[i,k] * W2[k,f]) * dinv[i], f in [0,32)
__global__ void k_gemm2(const float* __restrict__ a1, const float* __restrict__ W2,
                        const float* __restrict__ dinv, float* __restrict__ hs2, int N) {
    __shared__ float as[32][64];
    int tid = threadIdx.x;
    int rbase = blockIdx.x * 32;
    const float4* av = (const float4*)a1;  // row r at av[r*16 + c]
    for (int i = tid; i < 512; i += 256) {
        int r = i >> 4, c = i & 15;
        int rr = rbase + r;
        if (rr >= N) rr = N - 1;
        ((float4*)&as[r][0])[c] = av[(size_t)rr * 16 + c];
    }
    __syncthreads();
    int f = tid & 31;
    int rs = tid >> 5;  // 0..7
    float a0 = 0.f, a1_ = 0.f, a2 = 0.f, a3 = 0.f;
#pragma unroll 4
    for (int k = 0; k < 64; ++k) {
        float w = W2[k * 32 + f];
        a0 = fmaf(as[rs][k], w, a0);
        a1_ = fmaf(as[rs + 8][k], w, a1_);
        a2 = fmaf(as[rs + 16][k], w, a2);
        a3 = fmaf(as[rs + 24][k], w, a3);
    }
    int r;
    r = rbase + rs;      if (r < N) hs2[(size_t)r * 32 + f] = a0 * dinv[r];
    r = rbase + rs + 8;  if (r < N) hs2[(size_t)r * 32 + f] = a1_ * dinv[r];
    r = rbase + rs + 16; if (r < N) hs2[(size_t)r * 32 + f] = a2 * dinv[r];
    r = rbase + rs + 24; if (r < N) hs2[(size_t)r * 32 + f] = a3 * dinv[r];
}

// ---- layer 2 aggregation: 8 groups x 8 lanes, unroll 2 -> 16 rows in flight
__global__ void k_agg2(const float* __restrict__ hs2, const int* __restrict__ row_ptr,
                       const int* __restrict__ csr_src, const float* __restrict__ dinv,
                       const float* __restrict__ b2, float* __restrict__ out, int N) {
    int node = (blockIdx.x * blockDim.x + threadIdx.x) >> 6;
    if (node >= N) return;
    int lane = threadIdx.x & 63;
    int g = lane >> 3;   // edge slot 0..7
    int c = lane & 7;    // float4 column
    const float4* H = (const float4*)hs2;  // row i at H[i*8 + c]

    float4 acc = {0.f, 0.f, 0.f, 0.f}, accB = {0.f, 0.f, 0.f, 0.f};
    if (g == 0) acc = H[(size_t)node * 8 + c];  // self-loop

    int beg = row_ptr[node], end = row_ptr[node + 1];
    int e = beg + g;
    for (; e + 8 < end; e += 16) {
        int j0 = csr_src[e];
        int j1 = csr_src[e + 8];
        float4 v0 = H[(size_t)j0 * 8 + c];
        float4 v1 = H[(size_t)j1 * 8 + c];
        add4(acc, v0);
        add4(accB, v1);
    }
    if (e < end) {
        int j = csr_src[e];
        add4(acc, H[(size_t)j * 8 + c]);
    }
    add4(acc, accB);
    add4(acc, shfl_xor4(acc, 8));
    add4(acc, shfl_xor4(acc, 16));
    add4(acc, shfl_xor4(acc, 32));
    if (g == 0) {
        float s = dinv[node];
        float4 bv = ((const float4*)b2)[c];
        float4 o;
        o.x = fmaf(acc.x, s, bv.x);
        o.y = fmaf(acc.y, s, bv.y);
        o.z = fmaf(acc.z, s, bv.z);
        o.w = fmaf(acc.w, s, bv.w);
        ((float4*)out)[(size_t)node * 8 + c] = o;
    }
}

extern "C" void kernel_launch(void* const* d_in, const int* in_sizes, int n_in,
                              void* d_out, int out_size, void* d_ws, size_t ws_size,
                              hipStream_t stream) {
    const float* x  = (const float*)d_in[0];
    const int*   idx = (const int*)d_in[1];
    const float* W1 = (const float*)d_in[2];
    const float* b1 = (const float*)d_in[3];
    const float* W2 = (const float*)d_in[4];
    const float* b2 = (const float*)d_in[5];
    float* out = (float*)d_out;

    const int N = in_sizes[0] / 128;   // 100000
    const int E = in_sizes[1] / 2;     // 1600000

    // workspace layout (256B aligned)
    char* ws = (char*)d_ws;
    size_t off = 0;
    auto alloc = [&](size_t bytes) -> char* {
        char* p = ws + off;
        off = (off + bytes + 255) & ~(size_t)255;
        return p;
    };
    float* dinv    = (float*)alloc((size_t)N * 4);
    int*   counts  = (int*)alloc((size_t)N * 4);
    int*   cursor  = (int*)alloc((size_t)N * 4);
    int*   row_ptr = (int*)alloc((size_t)(N + 1) * 4);
    int*   bsums   = (int*)alloc(512 * 4);
    int*   boffs   = (int*)alloc(512 * 4);
    int*   csr_src = (int*)alloc((size_t)E * 4);
    float* hs1     = (float*)alloc((size_t)N * 64 * 4);
    float* a1      = (float*)alloc((size_t)N * 64 * 4);
    float* hs2     = hs1;  // reuse: hs1 dead after k_agg1

    const int nb  = (N + 255) / 256;            // scan blocks (391 <= 512)
    const int eb4 = ((E + 3) / 4 + BLK - 1) / BLK;  // 4 edges/thread

    hipMemsetAsync(counts, 0, (size_t)N * 4, stream);
    k_count<<<eb4, BLK, 0, stream>>>(idx, counts, E);
    k_scan1<<<nb, 256, 0, stream>>>(counts, bsums, dinv, N);
    k_scan2<<<1, 512, 0, stream>>>(bsums, boffs, nb);
    k_scan3<<<nb, 256, 0, stream>>>(counts, boffs, row_ptr, cursor, N, E);
    k_fill<<<eb4, BLK, 0, stream>>>(idx, row_ptr, cursor, csr_src, E);

    k_gemm1<<<(N + 15) / 16, 256, 0, stream>>>(x, W1, dinv, hs1, N);
    k_agg1<<<(N + 3) / 4, 256, 0, stream>>>(hs1, row_ptr, csr_src, dinv, b1, a1, N);
    k_gemm2<<<(N + 31) / 32, 256, 0, stream>>>(a1, W2, dinv, hs2, N);
    k_agg2<<<(N + 3) / 4, 256, 0, stream>>>(hs2, row_ptr, csr_src, dinv, b2, out, N);
}

// Round 4
// 340.346 us; speedup vs baseline: 1.3423x; 1.3423x over previous
//
#include <hip/hip_runtime.h>

// GCN 2-layer: x[N,128] -> GCNConv(W1[128,64], b1) -> ReLU -> GCNConv(W2[64,32], b2)
// norm = dinv[src]*dinv[dst] factorized: pre-scale h by dinv, aggregate, post-scale.
// R4: CSR build via bucketed multisplit. R3 showed k_fill is floor-limited by
// write-amplified partial-line HBM traffic (WRITE_SIZE 107MB for a 6.4MB array,
// random 4B stores+atomics across 8 non-coherent XCD L2s). Bucketing by dst>>10
// makes every random store/atomic local to one CU's LDS or one XCD's L2 region.

#define BLK 256
#define EPT 8            // edges/thread in hist & part
#define BSHIFT 10        // nodes per bucket
#define NPB 1024         // 1 << BSHIFT
#define MAXBUCK 512      // >= nbuck = ceil(N / NPB); N=100K -> 98

__device__ __forceinline__ float4 shfl_xor4(float4 v, int m) {
    v.x = __shfl_xor(v.x, m, 64);
    v.y = __shfl_xor(v.y, m, 64);
    v.z = __shfl_xor(v.z, m, 64);
    v.w = __shfl_xor(v.w, m, 64);
    return v;
}
__device__ __forceinline__ void add4(float4& a, const float4 b) {
    a.x += b.x; a.y += b.y; a.z += b.z; a.w += b.w;
}

// int64-layout detection (wave-uniform, L2-hot): odd 32-bit words of the first
// 16 index values are all zero iff indices are little-endian int64.
__device__ __forceinline__ bool detect64(const int* __restrict__ idx) {
    int z = 0;
#pragma unroll
    for (int i = 1; i < 32; i += 2) z |= idx[i];
    return z == 0;
}

// ---- pass A: per-bucket histogram (LDS-accumulated, 1 global atomic/bucket/block)
__global__ void k_hist(const int* __restrict__ idx, int* __restrict__ bucket_counts,
                       int E) {
    __shared__ int h[MAXBUCK];
    bool is64 = detect64(idx);
    for (int i = threadIdx.x; i < MAXBUCK; i += BLK) h[i] = 0;
    __syncthreads();
    int base = blockIdx.x * (BLK * EPT) + threadIdx.x;
#pragma unroll
    for (int k = 0; k < EPT; ++k) {
        int e = base + k * BLK;
        if (e < E) {
            int d = is64 ? idx[2 * (E + e)] : idx[E + e];
            atomicAdd(&h[d >> BSHIFT], 1);
        }
    }
    __syncthreads();
    for (int i = threadIdx.x; i < MAXBUCK; i += BLK)
        if (h[i]) atomicAdd(&bucket_counts[i], h[i]);
}

// ---- scan bucket counts -> bucket_base[nbuck+1], init cursors
__global__ void k_bscan(const int* __restrict__ bucket_counts, int* __restrict__ bucket_base,
                        int* __restrict__ bucket_cursor, int nbuck, int E) {
    __shared__ int s[MAXBUCK];
    int t = threadIdx.x;  // 512 threads
    s[t] = (t < nbuck) ? bucket_counts[t] : 0;
    __syncthreads();
    for (int st = 1; st < MAXBUCK; st <<= 1) {
        int v = (t >= st) ? s[t - st] : 0;
        __syncthreads();
        s[t] += v;
        __syncthreads();
    }
    int excl = (t == 0) ? 0 : s[t - 1];
    if (t < nbuck) { bucket_base[t] = excl; bucket_cursor[t] = excl; }
    if (t == 0) bucket_base[nbuck] = E;
}

// ---- pass B: partition edges by bucket; packed value = src | (dst&1023)<<17.
// Per-block per-bucket range reservation -> stores grouped into ~80B runs,
// each line written by (essentially) one block -> L2 write-combining.
__global__ void k_part(const int* __restrict__ idx, int* __restrict__ bucket_cursor,
                       int* __restrict__ edge_part, int E) {
    __shared__ int h[MAXBUCK];
    __shared__ int rbase[MAXBUCK];
    bool is64 = detect64(idx);
    for (int i = threadIdx.x; i < MAXBUCK; i += BLK) h[i] = 0;
    __syncthreads();
    int base = blockIdx.x * (BLK * EPT) + threadIdx.x;
    int dst[EPT], src[EPT];
#pragma unroll
    for (int k = 0; k < EPT; ++k) {
        int e = base + k * BLK;
        if (e < E) {
            dst[k] = is64 ? idx[2 * (E + e)] : idx[E + e];
            src[k] = is64 ? idx[2 * e] : idx[e];
            atomicAdd(&h[dst[k] >> BSHIFT], 1);
        } else {
            dst[k] = -1;
        }
    }
    __syncthreads();
    for (int i = threadIdx.x; i < MAXBUCK; i += BLK) {
        int c = h[i];
        rbase[i] = c ? atomicAdd(&bucket_cursor[i], c) : 0;
        h[i] = 0;
    }
    __syncthreads();
#pragma unroll
    for (int k = 0; k < EPT; ++k) {
        if (dst[k] >= 0) {
            int b = dst[k] >> BSHIFT;
            int r = atomicAdd(&h[b], 1);
            edge_part[rbase[b] + r] = src[k] | ((dst[k] & (NPB - 1)) << 17);
        }
    }
}

// ---- pass C: one workgroup per bucket. Per-node count/scan/cursor in LDS;
// emits row_ptr, dinv, and the final csr_src (random stores only within the
// bucket's ~64KB region owned by this CU -> each line evicted once).
__global__ void k_csr(const int* __restrict__ edge_part, const int* __restrict__ bucket_base,
                      int* __restrict__ row_ptr, float* __restrict__ dinv,
                      int* __restrict__ csr_src, int N, int E, int nbuck) {
    __shared__ int cnt[NPB];
    __shared__ int off[NPB];
    __shared__ int tsum[BLK];
    int b = blockIdx.x;
    int node0 = b << BSHIFT;
    int nn = min(NPB, N - node0);
    int ebeg = bucket_base[b], eend = bucket_base[b + 1];
    int t = threadIdx.x;
    for (int i = t; i < NPB; i += BLK) cnt[i] = 0;
    __syncthreads();
    for (int e = ebeg + t; e < eend; e += BLK)
        atomicAdd(&cnt[((unsigned)edge_part[e]) >> 17], 1);
    __syncthreads();
    // exclusive scan of cnt[NPB]: thread owns 4 consecutive entries
    int c0 = cnt[4 * t], c1 = cnt[4 * t + 1], c2 = cnt[4 * t + 2], c3 = cnt[4 * t + 3];
    tsum[t] = c0 + c1 + c2 + c3;
    __syncthreads();
    for (int st = 1; st < BLK; st <<= 1) {
        int v = (t >= st) ? tsum[t - st] : 0;
        __syncthreads();
        tsum[t] += v;
        __syncthreads();
    }
    int ex = (t == 0) ? 0 : tsum[t - 1];
    off[4 * t] = ex;
    off[4 * t + 1] = ex + c0;
    off[4 * t + 2] = ex + c0 + c1;
    off[4 * t + 3] = ex + c0 + c1 + c2;
    __syncthreads();
    // row_ptr + dinv (coalesced)
    for (int i = t; i < nn; i += BLK) {
        row_ptr[node0 + i] = ebeg + off[i];
        dinv[node0 + i] = rsqrtf((float)(cnt[i] + 1));  // +1 self-loop
    }
    if (b == nbuck - 1 && t == 0) row_ptr[N] = E;
    __syncthreads();
    // fill: off[] doubles as per-node cursor
    for (int e = ebeg + t; e < eend; e += BLK) {
        int p = edge_part[e];
        int dlo = ((unsigned)p) >> 17;
        int r = atomicAdd(&off[dlo], 1);
        csr_src[ebeg + r] = p & 0x1FFFF;
    }
}

// ---- layer 1 GEMM: hs1[i,f] = (sum_k x[i,k] * W1[k,f]) * dinv[i], f in [0,64)
__global__ void k_gemm1(const float* __restrict__ x, const float* __restrict__ W1,
                        const float* __restrict__ dinv, float* __restrict__ hs1, int N) {
    __shared__ float xs[16][128];
    int tid = threadIdx.x;
    int rbase = blockIdx.x * 16;
    const float4* xv = (const float4*)x;  // row r at xv[r*32 + c]
    for (int i = tid; i < 512; i += 256) {
        int r = i >> 5, c = i & 31;
        int rr = rbase + r;
        if (rr >= N) rr = N - 1;
        ((float4*)&xs[r][0])[c] = xv[(size_t)rr * 32 + c];
    }
    __syncthreads();
    int f = tid & 63;
    int rs = tid >> 6;  // 0..3
    float a0 = 0.f, a1_ = 0.f, a2 = 0.f, a3 = 0.f;
#pragma unroll 4
    for (int k = 0; k < 128; ++k) {
        float w = W1[k * 64 + f];
        a0 = fmaf(xs[rs][k], w, a0);
        a1_ = fmaf(xs[rs + 4][k], w, a1_);
        a2 = fmaf(xs[rs + 8][k], w, a2);
        a3 = fmaf(xs[rs + 12][k], w, a3);
    }
    int r;
    r = rbase + rs;      if (r < N) hs1[(size_t)r * 64 + f] = a0 * dinv[r];
    r = rbase + rs + 4;  if (r < N) hs1[(size_t)r * 64 + f] = a1_ * dinv[r];
    r = rbase + rs + 8;  if (r < N) hs1[(size_t)r * 64 + f] = a2 * dinv[r];
    r = rbase + rs + 12; if (r < N) hs1[(size_t)r * 64 + f] = a3 * dinv[r];
}

// ---- layer 1 aggregation: one wave per node; 4 groups x 16 lanes, unroll 2
// -> 8 independent 256B row gathers in flight per wave.
__global__ void k_agg1(const float* __restrict__ hs1, const int* __restrict__ row_ptr,
                       const int* __restrict__ csr_src, const float* __restrict__ dinv,
                       const float* __restrict__ b1, float* __restrict__ a1, int N) {
    int node = (blockIdx.x * blockDim.x + threadIdx.x) >> 6;
    if (node >= N) return;
    int lane = threadIdx.x & 63;
    int g = lane >> 4;    // edge slot 0..3
    int c = lane & 15;    // float4 column
    const float4* H = (const float4*)hs1;  // row i at H[i*16 + c]

    float4 acc = {0.f, 0.f, 0.f, 0.f}, accB = {0.f, 0.f, 0.f, 0.f};
    if (g == 0) acc = H[(size_t)node * 16 + c];  // self-loop (pre-scaled by dinv)

    int beg = row_ptr[node], end = row_ptr[node + 1];
    int e = beg + g;
    for (; e + 4 < end; e += 8) {
        int j0 = csr_src[e];
        int j1 = csr_src[e + 4];
        float4 v0 = H[(size_t)j0 * 16 + c];
        float4 v1 = H[(size_t)j1 * 16 + c];
        add4(acc, v0);
        add4(accB, v1);
    }
    if (e < end) {
        int j = csr_src[e];
        add4(acc, H[(size_t)j * 16 + c]);
    }
    add4(acc, accB);
    add4(acc, shfl_xor4(acc, 16));
    add4(acc, shfl_xor4(acc, 32));
    if (g == 0) {
        float s = dinv[node];
        float4 bv = ((const float4*)b1)[c];
        float4 o;
        o.x = fmaxf(fmaf(acc.x, s, bv.x), 0.f);
        o.y = fmaxf(fmaf(acc.y, s, bv.y), 0.f);
        o.z = fmaxf(fmaf(acc.z, s, bv.z), 0.f);
        o.w = fmaxf(fmaf(acc.w, s, bv.w), 0.f);
        ((float4*)a1)[(size_t)node * 16 + c] = o;
    }
}

// ---- layer 2 GEMM: hs2[i,f] = (sum_k a1[i,k] * W2[k,f]) * dinv[i], f in [0,32)
__global__ void k_gemm2(const float* __restrict__ a1, const float* __restrict__ W2,
                        const float* __restrict__ dinv, float* __restrict__ hs2, int N) {
    __shared__ float as[32][64];
    int tid = threadIdx.x;
    int rbase = blockIdx.x * 32;
    const float4* av = (const float4*)a1;  // row r at av[r*16 + c]
    for (int i = tid; i < 512; i += 256) {
        int r = i >> 4, c = i & 15;
        int rr = rbase + r;
        if (rr >= N) rr = N - 1;
        ((float4*)&as[r][0])[c] = av[(size_t)rr * 16 + c];
    }
    __syncthreads();
    int f = tid & 31;
    int rs = tid >> 5;  // 0..7
    float a0 = 0.f, a1_ = 0.f, a2 = 0.f, a3 = 0.f;
#pragma unroll 4
    for (int k = 0; k < 64; ++k) {
        float w = W2[k * 32 + f];
        a0 = fmaf(as[rs][k], w, a0);
        a1_ = fmaf(as[rs + 8][k], w, a1_);
        a2 = fmaf(as[rs + 16][k], w, a2);
        a3 = fmaf(as[rs + 24][k], w, a3);
    }
    int r;
    r = rbase + rs;      if (r < N) hs2[(size_t)r * 32 + f] = a0 * dinv[r];
    r = rbase + rs + 8;  if (r < N) hs2[(size_t)r * 32 + f] = a1_ * dinv[r];
    r = rbase + rs + 16; if (r < N) hs2[(size_t)r * 32 + f] = a2 * dinv[r];
    r = rbase + rs + 24; if (r < N) hs2[(size_t)r * 32 + f] = a3 * dinv[r];
}

// ---- layer 2 aggregation: 8 groups x 8 lanes, unroll 2 -> 16 rows in flight
__global__ void k_agg2(const float* __restrict__ hs2, const int* __restrict__ row_ptr,
                       const int* __restrict__ csr_src, const float* __restrict__ dinv,
                       const float* __restrict__ b2, float* __restrict__ out, int N) {
    int node = (blockIdx.x * blockDim.x + threadIdx.x) >> 6;
    if (node >= N) return;
    int lane = threadIdx.x & 63;
    int g = lane >> 3;   // edge slot 0..7
    int c = lane & 7;    // float4 column
    const float4* H = (const float4*)hs2;  // row i at H[i*8 + c]

    float4 acc = {0.f, 0.f, 0.f, 0.f}, accB = {0.f, 0.f, 0.f, 0.f};
    if (g == 0) acc = H[(size_t)node * 8 + c];  // self-loop

    int beg = row_ptr[node], end = row_ptr[node + 1];
    int e = beg + g;
    for (; e + 8 < end; e += 16) {
        int j0 = csr_src[e];
        int j1 = csr_src[e + 8];
        float4 v0 = H[(size_t)j0 * 8 + c];
        float4 v1 = H[(size_t)j1 * 8 + c];
        add4(acc, v0);
        add4(accB, v1);
    }
    if (e < end) {
        int j = csr_src[e];
        add4(acc, H[(size_t)j * 8 + c]);
    }
    add4(acc, accB);
    add4(acc, shfl_xor4(acc, 8));
    add4(acc, shfl_xor4(acc, 16));
    add4(acc, shfl_xor4(acc, 32));
    if (g == 0) {
        float s = dinv[node];
        float4 bv = ((const float4*)b2)[c];
        float4 o;
        o.x = fmaf(acc.x, s, bv.x);
        o.y = fmaf(acc.y, s, bv.y);
        o.z = fmaf(acc.z, s, bv.z);
        o.w = fmaf(acc.w, s, bv.w);
        ((float4*)out)[(size_t)node * 8 + c] = o;
    }
}

extern "C" void kernel_launch(void* const* d_in, const int* in_sizes, int n_in,
                              void* d_out, int out_size, void* d_ws, size_t ws_size,
                              hipStream_t stream) {
    const float* x  = (const float*)d_in[0];
    const int*   idx = (const int*)d_in[1];
    const float* W1 = (const float*)d_in[2];
    const float* b1 = (const float*)d_in[3];
    const float* W2 = (const float*)d_in[4];
    const float* b2 = (const float*)d_in[5];
    float* out = (float*)d_out;

    const int N = in_sizes[0] / 128;   // 100000 (< 2^17, required by packing)
    const int E = in_sizes[1] / 2;     // 1600000
    const int nbuck = (N + NPB - 1) >> BSHIFT;   // 98 (<= MAXBUCK)

    // workspace layout (256B aligned)
    char* ws = (char*)d_ws;
    size_t off = 0;
    auto alloc = [&](size_t bytes) -> char* {
        char* p = ws + off;
        off = (off + bytes + 255) & ~(size_t)255;
        return p;
    };
    float* dinv     = (float*)alloc((size_t)N * 4);
    int*   row_ptr  = (int*)alloc((size_t)(N + 1) * 4);
    int*   bcounts  = (int*)alloc(MAXBUCK * 4);
    int*   bbase    = (int*)alloc((MAXBUCK + 1) * 4);
    int*   bcursor  = (int*)alloc(MAXBUCK * 4);
    int*   csr_src  = (int*)alloc((size_t)E * 4);
    float* hs1      = (float*)alloc((size_t)N * 64 * 4);
    float* a1       = (float*)alloc((size_t)N * 64 * 4);
    float* hs2      = hs1;               // reuse: hs1 dead after k_agg1
    int*   edge_part = (int*)hs1;        // reuse: hs1 written only at k_gemm1

    const int ebk = (E + BLK * EPT - 1) / (BLK * EPT);  // 782

    hipMemsetAsync(bcounts, 0, MAXBUCK * 4, stream);
    k_hist<<<ebk, BLK, 0, stream>>>(idx, bcounts, E);
    k_bscan<<<1, MAXBUCK, 0, stream>>>(bcounts, bbase, bcursor, nbuck, E);
    k_part<<<ebk, BLK, 0, stream>>>(idx, bcursor, edge_part, E);
    k_csr<<<nbuck, BLK, 0, stream>>>(edge_part, bbase, row_ptr, dinv, csr_src, N, E, nbuck);

    k_gemm1<<<(N + 15) / 16, 256, 0, stream>>>(x, W1, dinv, hs1, N);
    k_agg1<<<(N + 3) / 4, 256, 0, stream>>>(hs1, row_ptr, csr_src, dinv, b1, a1, N);
    k_gemm2<<<(N + 31) / 32, 256, 0, stream>>>(a1, W2, dinv, hs2, N);
    k_agg2<<<(N + 3) / 4, 256, 0, stream>>>(hs2, row_ptr, csr_src, dinv, b2, out, N);
}

// Round 5
// 322.859 us; speedup vs baseline: 1.4151x; 1.0542x over previous
//
#include <hip/hip_runtime.h>

// GCN 2-layer: x[N,128] -> GCNConv(W1[128,64], b1) -> ReLU -> GCNConv(W2[64,32], b2)
// norm = dinv[src]*dinv[dst] factorized: pre-scale h by dinv, aggregate, post-scale.
// CSR build via bucketed multisplit (R4: killed write-amplified random stores).
// R5: hs1/hs2 stored as bf16 (fp32 accumulate) -> halves the random-gather bytes
// that dominate k_agg1/k_agg2 (R4: FETCH 190MB, HBM 44%, traffic-bound).

#define BLK 256
#define EPT 8            // edges/thread in hist & part
#define BSHIFT 10        // nodes per bucket
#define NPB 1024         // 1 << BSHIFT
#define MAXBUCK 128      // >= nbuck = ceil(N / NPB); N=100K -> 98

typedef unsigned int uint_t;
typedef unsigned short ushort_t;

__device__ __forceinline__ ushort_t f2bf(float x) {   // RNE float->bf16
    union { float f; uint_t u; } un; un.f = x;
    uint_t u = un.u;
    return (ushort_t)((u + 0x7fffu + ((u >> 16) & 1u)) >> 16);
}
__device__ __forceinline__ void bfacc(float* a, uint4 v) {  // 8 bf16 += into fp32
    a[0] += __uint_as_float(v.x << 16);
    a[1] += __uint_as_float(v.x & 0xffff0000u);
    a[2] += __uint_as_float(v.y << 16);
    a[3] += __uint_as_float(v.y & 0xffff0000u);
    a[4] += __uint_as_float(v.z << 16);
    a[5] += __uint_as_float(v.z & 0xffff0000u);
    a[6] += __uint_as_float(v.w << 16);
    a[7] += __uint_as_float(v.w & 0xffff0000u);
}

// int64-layout detection (wave-uniform, L2-hot): odd 32-bit words of the first
// 16 index values are all zero iff indices are little-endian int64.
__device__ __forceinline__ bool detect64(const int* __restrict__ idx) {
    int z = 0;
#pragma unroll
    for (int i = 1; i < 32; i += 2) z |= idx[i];
    return z == 0;
}

// ---- pass A: per-bucket histogram (LDS-accumulated, 1 global atomic/bucket/block)
__global__ void k_hist(const int* __restrict__ idx, int* __restrict__ bucket_counts,
                       int E) {
    __shared__ int h[MAXBUCK];
    bool is64 = detect64(idx);
    for (int i = threadIdx.x; i < MAXBUCK; i += BLK) h[i] = 0;
    __syncthreads();
    int base = blockIdx.x * (BLK * EPT) + threadIdx.x;
#pragma unroll
    for (int k = 0; k < EPT; ++k) {
        int e = base + k * BLK;
        if (e < E) {
            int d = is64 ? idx[2 * (E + e)] : idx[E + e];
            atomicAdd(&h[d >> BSHIFT], 1);
        }
    }
    __syncthreads();
    for (int i = threadIdx.x; i < MAXBUCK; i += BLK)
        if (h[i]) atomicAdd(&bucket_counts[i], h[i]);
}

// ---- scan bucket counts -> bucket_base[nbuck+1], init cursors
__global__ void k_bscan(const int* __restrict__ bucket_counts, int* __restrict__ bucket_base,
                        int* __restrict__ bucket_cursor, int nbuck, int E) {
    __shared__ int s[MAXBUCK];
    int t = threadIdx.x;  // MAXBUCK threads
    s[t] = (t < nbuck) ? bucket_counts[t] : 0;
    __syncthreads();
    for (int st = 1; st < MAXBUCK; st <<= 1) {
        int v = (t >= st) ? s[t - st] : 0;
        __syncthreads();
        s[t] += v;
        __syncthreads();
    }
    int excl = (t == 0) ? 0 : s[t - 1];
    if (t < nbuck) { bucket_base[t] = excl; bucket_cursor[t] = excl; }
    if (t == 0) bucket_base[nbuck] = E;
}

// ---- pass B: partition edges by bucket; packed value = src | (dst&1023)<<17.
__global__ void k_part(const int* __restrict__ idx, int* __restrict__ bucket_cursor,
                       int* __restrict__ edge_part, int E) {
    __shared__ int h[MAXBUCK];
    __shared__ int rbase[MAXBUCK];
    bool is64 = detect64(idx);
    for (int i = threadIdx.x; i < MAXBUCK; i += BLK) h[i] = 0;
    __syncthreads();
    int base = blockIdx.x * (BLK * EPT) + threadIdx.x;
    int dst[EPT], src[EPT];
#pragma unroll
    for (int k = 0; k < EPT; ++k) {
        int e = base + k * BLK;
        if (e < E) {
            dst[k] = is64 ? idx[2 * (E + e)] : idx[E + e];
            src[k] = is64 ? idx[2 * e] : idx[e];
            atomicAdd(&h[dst[k] >> BSHIFT], 1);
        } else {
            dst[k] = -1;
        }
    }
    __syncthreads();
    for (int i = threadIdx.x; i < MAXBUCK; i += BLK) {
        int c = h[i];
        rbase[i] = c ? atomicAdd(&bucket_cursor[i], c) : 0;
        h[i] = 0;
    }
    __syncthreads();
#pragma unroll
    for (int k = 0; k < EPT; ++k) {
        if (dst[k] >= 0) {
            int b = dst[k] >> BSHIFT;
            int r = atomicAdd(&h[b], 1);
            edge_part[rbase[b] + r] = src[k] | ((dst[k] & (NPB - 1)) << 17);
        }
    }
}

// ---- pass C: one workgroup per bucket; per-node count/scan/cursor in LDS;
// emits row_ptr, dinv, csr_src (random stores confined to this CU's ~64KB region).
__global__ void k_csr(const int* __restrict__ edge_part, const int* __restrict__ bucket_base,
                      int* __restrict__ row_ptr, float* __restrict__ dinv,
                      int* __restrict__ csr_src, int N, int E, int nbuck) {
    __shared__ int cnt[NPB];
    __shared__ int off[NPB];
    __shared__ int tsum[BLK];
    int b = blockIdx.x;
    int node0 = b << BSHIFT;
    int nn = min(NPB, N - node0);
    int ebeg = bucket_base[b], eend = bucket_base[b + 1];
    int t = threadIdx.x;
    for (int i = t; i < NPB; i += BLK) cnt[i] = 0;
    __syncthreads();
    for (int e = ebeg + t; e < eend; e += BLK)
        atomicAdd(&cnt[((unsigned)edge_part[e]) >> 17], 1);
    __syncthreads();
    int c0 = cnt[4 * t], c1 = cnt[4 * t + 1], c2 = cnt[4 * t + 2], c3 = cnt[4 * t + 3];
    tsum[t] = c0 + c1 + c2 + c3;
    __syncthreads();
    for (int st = 1; st < BLK; st <<= 1) {
        int v = (t >= st) ? tsum[t - st] : 0;
        __syncthreads();
        tsum[t] += v;
        __syncthreads();
    }
    int ex = (t == 0) ? 0 : tsum[t - 1];
    off[4 * t] = ex;
    off[4 * t + 1] = ex + c0;
    off[4 * t + 2] = ex + c0 + c1;
    off[4 * t + 3] = ex + c0 + c1 + c2;
    __syncthreads();
    for (int i = t; i < nn; i += BLK) {
        row_ptr[node0 + i] = ebeg + off[i];
        dinv[node0 + i] = rsqrtf((float)(cnt[i] + 1));  // +1 self-loop
    }
    if (b == nbuck - 1 && t == 0) row_ptr[N] = E;
    __syncthreads();
    for (int e = ebeg + t; e < eend; e += BLK) {
        int p = edge_part[e];
        int dlo = ((unsigned)p) >> 17;
        int r = atomicAdd(&off[dlo], 1);
        csr_src[ebeg + r] = p & 0x1FFFF;
    }
}

// ---- layer 1 GEMM: hs1[i,f] = bf16((sum_k x[i,k] * W1[k,f]) * dinv[i]), f in [0,64)
__global__ void k_gemm1(const float* __restrict__ x, const float* __restrict__ W1,
                        const float* __restrict__ dinv, ushort_t* __restrict__ hs1, int N) {
    __shared__ float xs[16][128];
    int tid = threadIdx.x;
    int rbase = blockIdx.x * 16;
    const float4* xv = (const float4*)x;  // row r at xv[r*32 + c]
    for (int i = tid; i < 512; i += 256) {
        int r = i >> 5, c = i & 31;
        int rr = rbase + r;
        if (rr >= N) rr = N - 1;
        ((float4*)&xs[r][0])[c] = xv[(size_t)rr * 32 + c];
    }
    __syncthreads();
    int f = tid & 63;
    int rs = tid >> 6;  // 0..3
    float a0 = 0.f, a1_ = 0.f, a2 = 0.f, a3 = 0.f;
#pragma unroll 4
    for (int k = 0; k < 128; ++k) {
        float w = W1[k * 64 + f];
        a0 = fmaf(xs[rs][k], w, a0);
        a1_ = fmaf(xs[rs + 4][k], w, a1_);
        a2 = fmaf(xs[rs + 8][k], w, a2);
        a3 = fmaf(xs[rs + 12][k], w, a3);
    }
    int r;
    r = rbase + rs;      if (r < N) hs1[(size_t)r * 64 + f] = f2bf(a0 * dinv[r]);
    r = rbase + rs + 4;  if (r < N) hs1[(size_t)r * 64 + f] = f2bf(a1_ * dinv[r]);
    r = rbase + rs + 8;  if (r < N) hs1[(size_t)r * 64 + f] = f2bf(a2 * dinv[r]);
    r = rbase + rs + 12; if (r < N) hs1[(size_t)r * 64 + f] = f2bf(a3 * dinv[r]);
}

// ---- layer 1 aggregation: one wave per node; 8 groups x 8 lanes, each lane a
// uint4 (8 bf16); unroll 2 -> 16 independent 128B row gathers in flight.
__global__ void k_agg1(const uint_t* __restrict__ hs1, const int* __restrict__ row_ptr,
                       const int* __restrict__ csr_src, const float* __restrict__ dinv,
                       const float* __restrict__ b1, float* __restrict__ a1, int N) {
    int node = (blockIdx.x * blockDim.x + threadIdx.x) >> 6;
    if (node >= N) return;
    int lane = threadIdx.x & 63;
    int g = lane >> 3;   // edge slot 0..7
    int c = lane & 7;    // uint4 column: features [8c, 8c+8)
    const uint4* H = (const uint4*)hs1;  // row i at H[i*8 + c]

    float acc[8] = {0.f, 0.f, 0.f, 0.f, 0.f, 0.f, 0.f, 0.f};
    if (g == 0) bfacc(acc, H[(size_t)node * 8 + c]);  // self-loop (pre-scaled)

    int beg = row_ptr[node], end = row_ptr[node + 1];
    int e = beg + g;
    for (; e + 8 < end; e += 16) {
        int j0 = csr_src[e];
        int j1 = csr_src[e + 8];
        uint4 v0 = H[(size_t)j0 * 8 + c];
        uint4 v1 = H[(size_t)j1 * 8 + c];
        bfacc(acc, v0);
        bfacc(acc, v1);
    }
    if (e < end) {
        int j = csr_src[e];
        bfacc(acc, H[(size_t)j * 8 + c]);
    }
#pragma unroll
    for (int m = 8; m <= 32; m <<= 1)
#pragma unroll
        for (int i = 0; i < 8; ++i) acc[i] += __shfl_xor(acc[i], m, 64);
    if (g == 0) {
        float s = dinv[node];
        const float4* B = (const float4*)b1;
        float4 bv0 = B[2 * c], bv1 = B[2 * c + 1];
        float4 o0, o1;
        o0.x = fmaxf(fmaf(acc[0], s, bv0.x), 0.f);
        o0.y = fmaxf(fmaf(acc[1], s, bv0.y), 0.f);
        o0.z = fmaxf(fmaf(acc[2], s, bv0.z), 0.f);
        o0.w = fmaxf(fmaf(acc[3], s, bv0.w), 0.f);
        o1.x = fmaxf(fmaf(acc[4], s, bv1.x), 0.f);
        o1.y = fmaxf(fmaf(acc[5], s, bv1.y), 0.f);
        o1.z = fmaxf(fmaf(acc[6], s, bv1.z), 0.f);
        o1.w = fmaxf(fmaf(acc[7], s, bv1.w), 0.f);
        float4* A = (float4*)a1;
        A[(size_t)node * 16 + 2 * c] = o0;
        A[(size_t)node * 16 + 2 * c + 1] = o1;
    }
}

// ---- layer 2 GEMM: hs2[i,f] = bf16((sum_k a1[i,k] * W2[k,f]) * dinv[i]), f in [0,32)
__global__ void k_gemm2(const float* __restrict__ a1, const float* __restrict__ W2,
                        const float* __restrict__ dinv, ushort_t* __restrict__ hs2, int N) {
    __shared__ float as[32][64];
    int tid = threadIdx.x;
    int rbase = blockIdx.x * 32;
    const float4* av = (const float4*)a1;  // row r at av[r*16 + c]
    for (int i = tid; i < 512; i += 256) {
        int r = i >> 4, c = i & 15;
        int rr = rbase + r;
        if (rr >= N) rr = N - 1;
        ((float4*)&as[r][0])[c] = av[(size_t)rr * 16 + c];
    }
    __syncthreads();
    int f = tid & 31;
    int rs = tid >> 5;  // 0..7
    float a0 = 0.f, a1_ = 0.f, a2 = 0.f, a3 = 0.f;
#pragma unroll 4
    for (int k = 0; k < 64; ++k) {
        float w = W2[k * 32 + f];
        a0 = fmaf(as[rs][k], w, a0);
        a1_ = fmaf(as[rs + 8][k], w, a1_);
        a2 = fmaf(as[rs + 16][k], w, a2);
        a3 = fmaf(as[rs + 24][k], w, a3);
    }
    int r;
    r = rbase + rs;      if (r < N) hs2[(size_t)r * 32 + f] = f2bf(a0 * dinv[r]);
    r = rbase + rs + 8;  if (r < N) hs2[(size_t)r * 32 + f] = f2bf(a1_ * dinv[r]);
    r = rbase + rs + 16; if (r < N) hs2[(size_t)r * 32 + f] = f2bf(a2 * dinv[r]);
    r = rbase + rs + 24; if (r < N) hs2[(size_t)r * 32 + f] = f2bf(a3 * dinv[r]);
}

// ---- layer 2 aggregation: 16 groups x 4 lanes (64B bf16 rows), unroll 2
// -> up to 32 independent row gathers in flight.
__global__ void k_agg2(const uint_t* __restrict__ hs2, const int* __restrict__ row_ptr,
                       const int* __restrict__ csr_src, const float* __restrict__ dinv,
                       const float* __restrict__ b2, float* __restrict__ out, int N) {
    int node = (blockIdx.x * blockDim.x + threadIdx.x) >> 6;
    if (node >= N) return;
    int lane = threadIdx.x & 63;
    int g = lane >> 2;   // edge slot 0..15
    int c = lane & 3;    // uint4 column: features [8c, 8c+8)
    const uint4* H = (const uint4*)hs2;  // row i at H[i*4 + c]

    float acc[8] = {0.f, 0.f, 0.f, 0.f, 0.f, 0.f, 0.f, 0.f};
    if (g == 0) bfacc(acc, H[(size_t)node * 4 + c]);  // self-loop

    int beg = row_ptr[node], end = row_ptr[node + 1];
    int e = beg + g;
    for (; e + 16 < end; e += 32) {
        int j0 = csr_src[e];
        int j1 = csr_src[e + 16];
        uint4 v0 = H[(size_t)j0 * 4 + c];
        uint4 v1 = H[(size_t)j1 * 4 + c];
        bfacc(acc, v0);
        bfacc(acc, v1);
    }
    if (e < end) {
        int j = csr_src[e];
        bfacc(acc, H[(size_t)j * 4 + c]);
    }
#pragma unroll
    for (int m = 4; m <= 32; m <<= 1)
#pragma unroll
        for (int i = 0; i < 8; ++i) acc[i] += __shfl_xor(acc[i], m, 64);
    if (g == 0) {
        float s = dinv[node];
        const float4* B = (const float4*)b2;
        float4 bv0 = B[2 * c], bv1 = B[2 * c + 1];
        float4 o0, o1;
        o0.x = fmaf(acc[0], s, bv0.x);
        o0.y = fmaf(acc[1], s, bv0.y);
        o0.z = fmaf(acc[2], s, bv0.z);
        o0.w = fmaf(acc[3], s, bv0.w);
        o1.x = fmaf(acc[4], s, bv1.x);
        o1.y = fmaf(acc[5], s, bv1.y);
        o1.z = fmaf(acc[6], s, bv1.z);
        o1.w = fmaf(acc[7], s, bv1.w);
        float4* O = (float4*)out;
        O[(size_t)node * 8 + 2 * c] = o0;
        O[(size_t)node * 8 + 2 * c + 1] = o1;
    }
}

extern "C" void kernel_launch(void* const* d_in, const int* in_sizes, int n_in,
                              void* d_out, int out_size, void* d_ws, size_t ws_size,
                              hipStream_t stream) {
    const float* x  = (const float*)d_in[0];
    const int*   idx = (const int*)d_in[1];
    const float* W1 = (const float*)d_in[2];
    const float* b1 = (const float*)d_in[3];
    const float* W2 = (const float*)d_in[4];
    const float* b2 = (const float*)d_in[5];
    float* out = (float*)d_out;

    const int N = in_sizes[0] / 128;   // 100000 (< 2^17, required by packing)
    const int E = in_sizes[1] / 2;     // 1600000
    const int nbuck = (N + NPB - 1) >> BSHIFT;   // 98 (<= MAXBUCK)

    // workspace layout (256B aligned)
    char* ws = (char*)d_ws;
    size_t off = 0;
    auto alloc = [&](size_t bytes) -> char* {
        char* p = ws + off;
        off = (off + bytes + 255) & ~(size_t)255;
        return p;
    };
    float* dinv     = (float*)alloc((size_t)N * 4);
    int*   row_ptr  = (int*)alloc((size_t)(N + 1) * 4);
    int*   bcounts  = (int*)alloc(MAXBUCK * 4);
    int*   bbase    = (int*)alloc((MAXBUCK + 1) * 4);
    int*   bcursor  = (int*)alloc(MAXBUCK * 4);
    int*   csr_src  = (int*)alloc((size_t)E * 4);
    ushort_t* hs1   = (ushort_t*)alloc((size_t)N * 64 * 2);  // bf16
    float* a1       = (float*)alloc((size_t)N * 64 * 4);
    ushort_t* hs2   = hs1;               // reuse: hs1 dead after k_agg1
    int*   edge_part = (int*)hs1;        // reuse: hs1 written only at k_gemm1

    const int ebk = (E + BLK * EPT - 1) / (BLK * EPT);  // 782

    hipMemsetAsync(bcounts, 0, MAXBUCK * 4, stream);
    k_hist<<<ebk, BLK, 0, stream>>>(idx, bcounts, E);
    k_bscan<<<1, MAXBUCK, 0, stream>>>(bcounts, bbase, bcursor, nbuck, E);
    k_part<<<ebk, BLK, 0, stream>>>(idx, bcursor, edge_part, E);
    k_csr<<<nbuck, BLK, 0, stream>>>(edge_part, bbase, row_ptr, dinv, csr_src, N, E, nbuck);

    k_gemm1<<<(N + 15) / 16, 256, 0, stream>>>(x, W1, dinv, hs1, N);
    k_agg1<<<(N + 3) / 4, 256, 0, stream>>>((const uint_t*)hs1, row_ptr, csr_src, dinv, b1, a1, N);
    k_gemm2<<<(N + 31) / 32, 256, 0, stream>>>(a1, W2, dinv, hs2, N);
    k_agg2<<<(N + 3) / 4, 256, 0, stream>>>((const uint_t*)hs2, row_ptr, csr_src, dinv, b2, out, N);
}